// Round 29
// baseline (127.027 us; speedup 1.0000x reference)
//
#include <hip/hip_runtime.h>
#include <hip/hip_bf16.h>
#include <cstdint>
#include <cstddef>

#define HIDDEN 768
#define HEADS 12
#define HD 64
#define SEQ 4096
#define NSPLIT 2

typedef __hip_bfloat16 bf16;
typedef short bf16x8 __attribute__((ext_vector_type(8)));
typedef float f32x4 __attribute__((ext_vector_type(4)));

// 0.125 (1/sqrt(64)) * log2(e): folded into Q so softmax runs in exp2 domain
#define QSCALE 0.18033688011112042f

static __device__ __forceinline__ void gload_lds16(const bf16* g, bf16* l) {
  __builtin_amdgcn_global_load_lds(
      (const __attribute__((address_space(1))) unsigned int*)(g),
      (__attribute__((address_space(3))) unsigned int*)(l), 16, 0, 0);
}

static __device__ __forceinline__ unsigned cvt_pk_bf16(float lo, float hi) {
  unsigned r;
  asm("v_cvt_pk_bf16_f32 %0, %1, %2" : "=v"(r) : "v"(lo), "v"(hi));
  return r;
}

static __device__ __forceinline__ float b2f(short s) {
  union { unsigned u; float f; } v;
  v.u = ((unsigned)(unsigned short)s) << 16;
  return v.f;
}

static __device__ __forceinline__ float max3f(float a, float b, float c) {
  return fmaxf(fmaxf(a, b), c);   // clang fuses to v_max3_f32
}

// ---------------- fused prep: x->bf16 + all weight transposes ----------------
// grid: [0,3072) cvt_x; [3072,3504) Wq/Wk/Wv tiles; [3504,3648) Wo tiles.
__global__ __launch_bounds__(256) void prep_kernel(
    const float* __restrict__ x, const float* __restrict__ Wq,
    const float* __restrict__ Wk, const float* __restrict__ Wv,
    const float* __restrict__ Wo, bf16* __restrict__ xb,
    bf16* __restrict__ Wt, bf16* __restrict__ Wot) {
  __shared__ float t[64][65];
  int i = blockIdx.x;
  if (i < 3072) {
    int idx = i * 256 + threadIdx.x;
    float4 v = ((const float4*)x)[idx];
    union { bf16 h[4]; short4 s4; } u;
    u.h[0] = __float2bfloat16(v.x);
    u.h[1] = __float2bfloat16(v.y);
    u.h[2] = __float2bfloat16(v.z);
    u.h[3] = __float2bfloat16(v.w);
    ((short4*)xb)[idx] = u.s4;
    return;
  }
  i -= 3072;
  const float* src;
  bf16* dst;
  int R, C, tr, tc;
  if (i < 432) {                     // Wq/Wk/Wv: per-head [768][64] -> [64][768]
    int m = i / 144;
    int j = i - m * 144;
    int b = j / 12;
    tr = j - b * 12; tc = 0;
    src = (m == 0 ? Wq : m == 1 ? Wk : Wv) + (size_t)b * 768 * 64;
    dst = Wt + (size_t)m * 589824 + (size_t)b * 768 * 64;
    R = 768; C = 64;
  } else {                           // Wo: [768][768] -> [768][768]^T
    int j = i - 432;
    tr = j / 12; tc = j - tr * 12;
    src = Wo; dst = Wot; R = 768; C = 768;
  }
  int r0 = tr << 6, c0 = tc << 6;
#pragma unroll
  for (int k = threadIdx.x; k < 4096; k += 256) {
    int r = k >> 6, c = k & 63;
    t[r][c] = src[(size_t)(r0 + r) * C + c0 + c];
  }
  __syncthreads();
#pragma unroll
  for (int k = threadIdx.x; k < 4096; k += 256) {
    int c = k >> 6, r = k & 63;
    dst[(size_t)(c0 + c) * R + r0 + r] = __float2bfloat16(t[r][c]);
  }
}

// -- GEMM-QKV (64x64 tile, BK=64, XOR-swizzled LDS): [Q|K|V] = xb*Wt^T + bias -
// Same body as the validated gemm64 (R28), QKV epilogue. Grid 64x36 = 2304
// blocks = 9/CU of work; LDS ~35 KB -> 4 blocks/CU resident (16 waves/CU,
// vs 12 at the 128x64 shape). Per-element K-accumulation order unchanged ->
// bitwise-identical Q/K/Vt.
__global__ __launch_bounds__(256) void gemmqkv_kernel(
    const bf16* __restrict__ A, const bf16* __restrict__ Bt,
    const float* __restrict__ bq, const float* __restrict__ bk,
    const float* __restrict__ bv,
    bf16* __restrict__ Qb, bf16* __restrict__ Kb, bf16* __restrict__ Vt) {
  const int K = HIDDEN;
  __shared__ bf16 sA[2][64 * 64];
  __shared__ bf16 sB[2][64 * 64];
  __shared__ bf16 strans[4][16][20];

  int bid = blockIdx.x;
  int bm = bid / 36, bn = bid - bm * 36;
  int tid = threadIdx.x;
  int w = tid >> 6, l = tid & 63;
  int wr = w >> 1, wc = w & 1;
  int l15 = l & 15, g = l >> 4;
  const int sw = l15 & 7;

  const bf16* Ab = A + (size_t)bm * 64 * K;
  const bf16* Bb = Bt + (size_t)bn * 64 * K;

  int sr = tid >> 3;                    // staging row 0..31
  int scs = ((tid & 7) ^ (sr & 7)) << 3; // pre-swizzled source col (elems)

  f32x4 acc[2][2] = {};
  int NT = K >> 6;                       // 12
  int cur = 0;

  auto stage = [&](int buf, int kt) {
    const bf16* ga = Ab + (size_t)sr * K + kt * 64 + scs;
    bf16* la = &sA[buf][w << 9];
    gload_lds16(ga, la);
    gload_lds16(ga + (size_t)32 * K, la + 2048);
    const bf16* gb = Bb + (size_t)sr * K + kt * 64 + scs;
    bf16* lb = &sB[buf][w << 9];
    gload_lds16(gb, lb);
    gload_lds16(gb + (size_t)32 * K, lb + 2048);
  };

  stage(0, 0);
  for (int kt = 0; kt < NT; ++kt) {
    __syncthreads();
    if (kt + 1 < NT) stage(cur ^ 1, kt + 1);
    const bf16* pa = &sA[cur][0];
    const bf16* pb = &sB[cur][0];
    bf16x8 af[2][2], bfr[2][2];
#pragma unroll
    for (int kh = 0; kh < 2; ++kh) {
#pragma unroll
      for (int m = 0; m < 2; ++m)
        af[kh][m] = *(const bf16x8*)&pa[(wr * 32 + m * 16 + l15) * 64 +
                                        (((kh * 4 + g) ^ sw) << 3)];
#pragma unroll
      for (int n = 0; n < 2; ++n)
        bfr[kh][n] = *(const bf16x8*)&pb[(wc * 32 + n * 16 + l15) * 64 +
                                         (((kh * 4 + g) ^ sw) << 3)];
    }
#pragma unroll
    for (int kh = 0; kh < 2; ++kh)
#pragma unroll
      for (int m = 0; m < 2; ++m)
#pragma unroll
        for (int n = 0; n < 2; ++n)
          acc[m][n] = __builtin_amdgcn_mfma_f32_16x16x32_bf16(af[kh][m], bfr[kh][n],
                                                              acc[m][n], 0, 0, 0);
    cur ^= 1;
  }

  const int mat = bn / 12;           // 0=Q 1=K 2=V (12 head-tiles per matrix)
  const int h = bn - mat * 12;
  const float* bias = (mat == 0) ? bq : (mat == 1) ? bk : bv;
  const float scl = (mat == 0) ? QSCALE : 1.0f;

#pragma unroll
  for (int n = 0; n < 2; ++n) {
    int e = wc * 32 + n * 16 + l15;  // 0..63 within the head
    float bb = bias[h * 64 + e];
#pragma unroll
    for (int m = 0; m < 2; ++m) {
      int s0m = bm * 64 + wr * 32 + m * 16;
      if (mat < 2) {
        bf16* dst = (mat == 0 ? Qb : Kb) + (size_t)h * SEQ * 64;
#pragma unroll
        for (int r = 0; r < 4; ++r)
          dst[(size_t)(s0m + g * 4 + r) * 64 + e] = __float2bfloat16((acc[m][n][r] + bb) * scl);
      } else {
#pragma unroll
        for (int r = 0; r < 4; ++r)
          strans[w][g * 4 + r][l15] = __float2bfloat16(acc[m][n][r] + bb);
        int e0f = e - l15;
        bf16* dst = Vt + (size_t)h * SEQ * 64;
#pragma unroll
        for (int r = 0; r < 4; ++r) {
          bf16 val = strans[w][l15][g * 4 + r];
          dst[(size_t)(e0f + g * 4 + r) * SEQ + s0m + l15] = val;
        }
      }
    }
  }
}

// ---- GEMM64 (64x64 tile, BK=64, XOR-swizzled LDS): out = ctx*Wot^T + bo -----
__global__ __launch_bounds__(256) void gemm64_kernel(
    const bf16* __restrict__ A, const bf16* __restrict__ Bt,
    int K, int ntn, const float* __restrict__ bo, float* __restrict__ outp) {
  __shared__ bf16 sA[2][64 * 64];
  __shared__ bf16 sB[2][64 * 64];

  int bid = blockIdx.x;
  int bm = bid / ntn, bn = bid - bm * ntn;
  int tid = threadIdx.x;
  int w = tid >> 6, l = tid & 63;
  int wr = w >> 1, wc = w & 1;
  int l15 = l & 15, g = l >> 4;
  const int sw = l15 & 7;

  const bf16* Ab = A + (size_t)bm * 64 * K;
  const bf16* Bb = Bt + (size_t)bn * 64 * K;

  int sr = tid >> 3;                    // staging row 0..31
  int scs = ((tid & 7) ^ (sr & 7)) << 3; // pre-swizzled source col (elems)

  f32x4 acc[2][2] = {};
  int NT = K >> 6;                       // 12
  int cur = 0;

  auto stage = [&](int buf, int kt) {
    const bf16* ga = Ab + (size_t)sr * K + kt * 64 + scs;
    bf16* la = &sA[buf][w << 9];
    gload_lds16(ga, la);
    gload_lds16(ga + (size_t)32 * K, la + 2048);
    const bf16* gb = Bb + (size_t)sr * K + kt * 64 + scs;
    bf16* lb = &sB[buf][w << 9];
    gload_lds16(gb, lb);
    gload_lds16(gb + (size_t)32 * K, lb + 2048);
  };

  stage(0, 0);
  for (int kt = 0; kt < NT; ++kt) {
    __syncthreads();
    if (kt + 1 < NT) stage(cur ^ 1, kt + 1);
    const bf16* pa = &sA[cur][0];
    const bf16* pb = &sB[cur][0];
    bf16x8 af[2][2], bfr[2][2];
#pragma unroll
    for (int kh = 0; kh < 2; ++kh) {
#pragma unroll
      for (int m = 0; m < 2; ++m)
        af[kh][m] = *(const bf16x8*)&pa[(wr * 32 + m * 16 + l15) * 64 +
                                        (((kh * 4 + g) ^ sw) << 3)];
#pragma unroll
      for (int n = 0; n < 2; ++n)
        bfr[kh][n] = *(const bf16x8*)&pb[(wc * 32 + n * 16 + l15) * 64 +
                                         (((kh * 4 + g) ^ sw) << 3)];
    }
#pragma unroll
    for (int kh = 0; kh < 2; ++kh)
#pragma unroll
      for (int m = 0; m < 2; ++m)
#pragma unroll
        for (int n = 0; n < 2; ++n)
          acc[m][n] = __builtin_amdgcn_mfma_f32_16x16x32_bf16(af[kh][m], bfr[kh][n],
                                                              acc[m][n], 0, 0, 0);
    cur ^= 1;
  }

#pragma unroll
  for (int n = 0; n < 2; ++n) {
    int j = bn * 64 + wc * 32 + n * 16 + l15;
    float bb = bo[j];
#pragma unroll
    for (int m = 0; m < 2; ++m) {
      int s0m = bm * 64 + wr * 32 + m * 16;
#pragma unroll
      for (int r = 0; r < 4; ++r)
        outp[(size_t)(s0m + g * 4 + r) * HIDDEN + j] = acc[m][n][r] + bb;
    }
  }
}

// ---------------- flash attention v19: split-KV x2 (R23 winner, unchanged) ---
__global__ __launch_bounds__(512, 8) void flash_kernel(
    const bf16* __restrict__ Qb, const bf16* __restrict__ Kb,
    const bf16* __restrict__ Vt, bf16* __restrict__ partC,
    float* __restrict__ partM, float* __restrict__ partL) {
  __shared__ bf16 sK[2][64 * 64];   // [t][e], 128B rows, swizzled
  __shared__ bf16 sV[2][64 * 64];   // [e][t], 128B rows, swizzled

  const int head = blockIdx.y;
  const int split = blockIdx.z;
  const int w = threadIdx.x >> 6, l = threadIdx.x & 63;
  const int l15 = l & 15, g = l >> 4;
  const int sw = l15 & 7;
  const int q0w = blockIdx.x * 128 + w * 16;

  const bf16* Qh = Qb + (size_t)head * SEQ * 64;
  const bf16* Kh = Kb + (size_t)head * SEQ * 64;
  const bf16* Vh = Vt + (size_t)head * SEQ * 64;   // [64][SEQ]

  // Q as B-operand: lane holds Q[col=q0w+l15][k-slice g]
  bf16x8 aq[2];
  aq[0] = *(const bf16x8*)&Qh[(size_t)(q0w + l15) * 64 + g * 8];
  aq[1] = *(const bf16x8*)&Qh[(size_t)(q0w + l15) * 64 + 32 + g * 8];

  float mrun = -1e30f, lsum = 0.f;   // mrun row-uniform (updated only in branch)
  f32x4 cacc[4] = {};

  const int lr8 = l >> 3;            // row-in-call 0..7
  const int csrc = (l & 7) ^ lr8;    // pre-swizzled source chunk

  // wave w stages K rows [w*8, w*8+8) and V rows [w*8, w*8+8)
  auto stage = [&](int buf, int kt) {
    int t0 = kt * 64;
    const bf16* gk = Kh + (size_t)(t0 + w * 8 + lr8) * 64 + csrc * 8;
    gload_lds16(gk, &sK[buf][(w * 8) * 64]);
    const bf16* gv = Vh + (size_t)(w * 8 + lr8) * SEQ + t0 + csrc * 8;
    gload_lds16(gv, &sV[buf][(w * 8) * 64]);
  };

  const int kt0 = split * (SEQ / 64 / NSPLIT);
  stage(0, kt0);

#pragma unroll
  for (int it = 0; it < SEQ / 64 / NSPLIT; ++it) {
    const int kt = kt0 + it;
    __syncthreads();               // drains prev stage (vmcnt) + protects buffers
    if (it + 1 < SEQ / 64 / NSPLIT) stage((it + 1) & 1, kt + 1);
    const bf16* kb = &sK[it & 1][0];   // static LDS base after unroll
    const bf16* vb = &sV[it & 1][0];

    // ---- S^T = K·Q^T: lane holds S[t=n*16+g*4+r][q=l15] ----
    f32x4 sc8[4] = {};
    __builtin_amdgcn_s_setprio(1);
#pragma unroll
    for (int n = 0; n < 4; ++n) {
      bf16x8 b0 = *(const bf16x8*)&kb[(n * 16 + l15) * 64 + (g ^ sw) * 8];
      bf16x8 b1 = *(const bf16x8*)&kb[(n * 16 + l15) * 64 + ((4 + g) ^ sw) * 8];
      sc8[n] = __builtin_amdgcn_mfma_f32_16x16x32_bf16(b0, aq[0], sc8[n], 0, 0, 0);
      sc8[n] = __builtin_amdgcn_mfma_f32_16x16x32_bf16(b1, aq[1], sc8[n], 0, 0, 0);
    }
    __builtin_amdgcn_s_setprio(0);

    // ---- lane-local quarter max (max3 groups, NO shuffles) ----
    float m0 = max3f(sc8[0][0], sc8[0][1], sc8[0][2]);
    float m1 = max3f(sc8[0][3], sc8[1][0], sc8[1][1]);
    float m2 = max3f(sc8[1][2], sc8[1][3], sc8[2][0]);
    float m3 = max3f(sc8[2][1], sc8[2][2], sc8[2][3]);
    float m4 = max3f(sc8[3][0], sc8[3][1], sc8[3][2]);
    float qmax = fmaxf(max3f(m0, m1, m2), max3f(m3, m4, sc8[3][3]));

    // ---- lazy defer-rescale: full row reduce only inside the rare branch ----
    if (__any(qmax > mrun + 8.0f)) {
      float vm = qmax;
      vm = fmaxf(vm, __shfl_xor(vm, 16));
      vm = fmaxf(vm, __shfl_xor(vm, 32));
      float mn = fmaxf(mrun, vm);
      float a = __builtin_amdgcn_exp2f(mrun - mn);
      mrun = mn;
      lsum *= a;
      float aqr[4];
#pragma unroll
      for (int r = 0; r < 4; ++r) aqr[r] = __shfl(a, g * 4 + r);
#pragma unroll
      for (int f = 0; f < 4; ++f)
#pragma unroll
        for (int r = 0; r < 4; ++r) cacc[f][r] *= aqr[r];
    }

    // ---- P = exp2(S - m), packed in-register ----
    unsigned X[4][2];
    float ls0 = 0.f, ls1 = 0.f;
#pragma unroll
    for (int n = 0; n < 4; ++n) {
#pragma unroll
      for (int h = 0; h < 2; ++h) {
        float p0 = __builtin_amdgcn_exp2f(sc8[n][2 * h] - mrun);
        float p1 = __builtin_amdgcn_exp2f(sc8[n][2 * h + 1] - mrun);
        ls0 += p0; ls1 += p1;
        X[n][h] = cvt_pk_bf16(p0, p1);
      }
    }
    lsum += ls0 + ls1;

    // ---- route packed P into PV A-frags (permlane-only, R15-validated) ----
#pragma unroll
    for (int kkl = 0; kkl < 2; ++kkl) {
      unsigned P0 = X[2 * kkl][0], Q0 = X[2 * kkl + 1][0];
      unsigned P1 = X[2 * kkl][1], Q1 = X[2 * kkl + 1][1];
      asm("v_permlane32_swap_b32 %0, %1" : "+v"(P0), "+v"(Q0));
      asm("v_permlane32_swap_b32 %0, %1" : "+v"(P1), "+v"(Q1));
      asm("v_permlane16_swap_b32 %0, %1" : "+v"(P0), "+v"(Q0));
      asm("v_permlane16_swap_b32 %0, %1" : "+v"(P1), "+v"(Q1));
      union { unsigned u[4]; bf16x8 v8; } ap;
      ap.u[0] = P0;
      ap.u[1] = P1;
      ap.u[2] = Q0;
      ap.u[3] = Q1;
      __builtin_amdgcn_s_setprio(1);
#pragma unroll
      for (int f = 0; f < 4; ++f) {
        bf16x8 bv8 = *(const bf16x8*)&vb[(f * 16 + l15) * 64 + ((kkl * 4 + g) ^ sw) * 8];
        cacc[f] = __builtin_amdgcn_mfma_f32_16x16x32_bf16(ap.v8, bv8, cacc[f], 0, 0, 0);
      }
      __builtin_amdgcn_s_setprio(0);
    }
  }

  // ---- epilogue: reduce l across g (R15 shfl_xor), store partials ----
  float s = lsum;
  s += __shfl_xor(s, 16);
  s += __shfl_xor(s, 32);

  bf16* pcw = partC + (size_t)split * SEQ * HIDDEN;
#pragma unroll
  for (int f = 0; f < 4; ++f)
#pragma unroll
    for (int r = 0; r < 4; ++r)
      pcw[(size_t)(q0w + g * 4 + r) * HIDDEN + head * 64 + f * 16 + l15] =
          __float2bfloat16(cacc[f][r]);
  if (l < 16) {
    size_t mi = (size_t)split * HEADS * SEQ + (size_t)head * SEQ + q0w + l15;
    partM[mi] = mrun;
    partL[mi] = s;
  }
}

// ---------------- split-KV combine (NSPLIT-way exact merge, bf16 partials) ----
__global__ __launch_bounds__(256) void combine_kernel(
    const bf16* __restrict__ partC, const float* __restrict__ partM,
    const float* __restrict__ partL, bf16* __restrict__ ctx) {
  int i = blockIdx.x * 256 + threadIdx.x;   // 4 elems per thread
  int idx = i * 4;
  int s = idx / HIDDEN, c = idx - s * HIDDEN;
  int h = c >> 6;
  size_t mi = (size_t)h * SEQ + s;
  float m[NSPLIT], lv[NSPLIT];
  float ms = -1e30f;
#pragma unroll
  for (int sp = 0; sp < NSPLIT; ++sp) {
    m[sp] = partM[(size_t)sp * HEADS * SEQ + mi];
    lv[sp] = partL[(size_t)sp * HEADS * SEQ + mi];
    ms = fmaxf(ms, m[sp]);
  }
  float wgt[NSPLIT];
  float denom = 0.f;
#pragma unroll
  for (int sp = 0; sp < NSPLIT; ++sp) {
    wgt[sp] = __builtin_amdgcn_exp2f(m[sp] - ms);
    denom += lv[sp] * wgt[sp];
  }
  float inv = 1.0f / denom;
  float ax = 0.f, ay = 0.f, az = 0.f, aw = 0.f;
#pragma unroll
  for (int sp = 0; sp < NSPLIT; ++sp) {
    short4 c4 = ((const short4*)(partC + (size_t)sp * SEQ * HIDDEN))[i];
    ax += b2f(c4.x) * wgt[sp];
    ay += b2f(c4.y) * wgt[sp];
    az += b2f(c4.z) * wgt[sp];
    aw += b2f(c4.w) * wgt[sp];
  }
  union { bf16 h4[4]; short4 s4; } u;
  u.h4[0] = __float2bfloat16(ax * inv);
  u.h4[1] = __float2bfloat16(ay * inv);
  u.h4[2] = __float2bfloat16(az * inv);
  u.h4[3] = __float2bfloat16(aw * inv);
  ((short4*)ctx)[i] = u.s4;
}

// ---------------- launcher ----------------
extern "C" void kernel_launch(void* const* d_in, const int* in_sizes, int n_in,
                              void* d_out, int out_size, void* d_ws, size_t ws_size,
                              hipStream_t stream) {
  const float* x = (const float*)d_in[0];
  const float* Wq = (const float*)d_in[1];
  const float* Wk = (const float*)d_in[2];
  const float* Wv = (const float*)d_in[3];
  const float* bq = (const float*)d_in[4];
  const float* bk = (const float*)d_in[5];
  const float* bv = (const float*)d_in[6];
  const float* Wo = (const float*)d_in[7];
  const float* bo = (const float*)d_in[8];
  float* outp = (float*)d_out;

  char* ws = (char*)d_ws;
  bf16* xb = (bf16*)ws;   ws += (size_t)SEQ * HIDDEN * 2;
  bf16* Wt = (bf16*)ws;   ws += (size_t)3 * HIDDEN * HIDDEN * 2;
  bf16* Wot = (bf16*)ws;  ws += (size_t)HIDDEN * HIDDEN * 2;
  bf16* Qb = (bf16*)ws;   ws += (size_t)SEQ * HIDDEN * 2;
  bf16* Kb = (bf16*)ws;   ws += (size_t)SEQ * HIDDEN * 2;
  bf16* Vt = (bf16*)ws;   ws += (size_t)SEQ * HIDDEN * 2;
  bf16* ctx = (bf16*)ws;  ws += (size_t)SEQ * HIDDEN * 2;
  bf16* partC = (bf16*)ws;  ws += (size_t)NSPLIT * SEQ * HIDDEN * 2;
  float* partM = (float*)ws; ws += (size_t)NSPLIT * HEADS * SEQ * 4;
  float* partL = (float*)ws; ws += (size_t)NSPLIT * HEADS * SEQ * 4;

  prep_kernel<<<3648, 256, 0, stream>>>(x, Wq, Wk, Wv, Wo, xb, Wt, Wot);

  gemmqkv_kernel<<<64 * 36, 256, 0, stream>>>(xb, Wt, bq, bk, bv, Qb, Kb, Vt);

  flash_kernel<<<dim3(SEQ / 128, HEADS, NSPLIT), 512, 0, stream>>>(Qb, Kb, Vt,
                                                                   partC, partM, partL);
  combine_kernel<<<SEQ * HIDDEN / 4 / 256, 256, 0, stream>>>(partC, partM, partL, ctx);

  gemm64_kernel<<<64 * 12, 256, 0, stream>>>(ctx, Wot, 768, 12, bo, outp);
}

// Round 30
// 121.568 us; speedup vs baseline: 1.0449x; 1.0449x over previous
//
#include <hip/hip_runtime.h>
#include <hip/hip_bf16.h>
#include <cstdint>
#include <cstddef>

#define HIDDEN 768
#define HEADS 12
#define HD 64
#define SEQ 4096
#define NSPLIT 2

typedef __hip_bfloat16 bf16;
typedef short bf16x8 __attribute__((ext_vector_type(8)));
typedef float f32x4 __attribute__((ext_vector_type(4)));

// 0.125 (1/sqrt(64)) * log2(e): folded into Q so softmax runs in exp2 domain
#define QSCALE 0.18033688011112042f

static __device__ __forceinline__ void gload_lds16(const bf16* g, bf16* l) {
  __builtin_amdgcn_global_load_lds(
      (const __attribute__((address_space(1))) unsigned int*)(g),
      (__attribute__((address_space(3))) unsigned int*)(l), 16, 0, 0);
}

static __device__ __forceinline__ unsigned cvt_pk_bf16(float lo, float hi) {
  unsigned r;
  asm("v_cvt_pk_bf16_f32 %0, %1, %2" : "=v"(r) : "v"(lo), "v"(hi));
  return r;
}

static __device__ __forceinline__ float b2f(short s) {
  union { unsigned u; float f; } v;
  v.u = ((unsigned)(unsigned short)s) << 16;
  return v.f;
}

static __device__ __forceinline__ float max3f(float a, float b, float c) {
  return fmaxf(fmaxf(a, b), c);   // clang fuses to v_max3_f32
}

// ---------------- fused prep: x->bf16 + all weight transposes ----------------
// grid: [0,3072) cvt_x; [3072,3504) Wq/Wk/Wv tiles; [3504,3648) Wo tiles.
__global__ __launch_bounds__(256) void prep_kernel(
    const float* __restrict__ x, const float* __restrict__ Wq,
    const float* __restrict__ Wk, const float* __restrict__ Wv,
    const float* __restrict__ Wo, bf16* __restrict__ xb,
    bf16* __restrict__ Wt, bf16* __restrict__ Wot) {
  __shared__ float t[64][65];
  int i = blockIdx.x;
  if (i < 3072) {
    int idx = i * 256 + threadIdx.x;
    float4 v = ((const float4*)x)[idx];
    union { bf16 h[4]; short4 s4; } u;
    u.h[0] = __float2bfloat16(v.x);
    u.h[1] = __float2bfloat16(v.y);
    u.h[2] = __float2bfloat16(v.z);
    u.h[3] = __float2bfloat16(v.w);
    ((short4*)xb)[idx] = u.s4;
    return;
  }
  i -= 3072;
  const float* src;
  bf16* dst;
  int R, C, tr, tc;
  if (i < 432) {                     // Wq/Wk/Wv: per-head [768][64] -> [64][768]
    int m = i / 144;
    int j = i - m * 144;
    int b = j / 12;
    tr = j - b * 12; tc = 0;
    src = (m == 0 ? Wq : m == 1 ? Wk : Wv) + (size_t)b * 768 * 64;
    dst = Wt + (size_t)m * 589824 + (size_t)b * 768 * 64;
    R = 768; C = 64;
  } else {                           // Wo: [768][768] -> [768][768]^T
    int j = i - 432;
    tr = j / 12; tc = j - tr * 12;
    src = Wo; dst = Wot; R = 768; C = 768;
  }
  int r0 = tr << 6, c0 = tc << 6;
#pragma unroll
  for (int k = threadIdx.x; k < 4096; k += 256) {
    int r = k >> 6, c = k & 63;
    t[r][c] = src[(size_t)(r0 + r) * C + c0 + c];
  }
  __syncthreads();
#pragma unroll
  for (int k = threadIdx.x; k < 4096; k += 256) {
    int c = k >> 6, r = k & 63;
    dst[(size_t)(c0 + c) * R + r0 + r] = __float2bfloat16(t[r][c]);
  }
}

// ------- GEMM-QKV (128x64 tile, BK=64, XOR-swizzled LDS): [Q|K|V] ------------
// BK=64 halves the K-iterations (24->12 barrier drains). LDS rows are 128B so
// a linear layout would be a 16-way bank conflict on ds_read_b128; the flash
// swizzle (chunk ^= row&7, applied via pre-swizzled GLOBAL source + XOR on the
// read side) makes it conflict-free. MFMA K-order is ascending chunk-by-chunk
// -> bitwise-identical output to the BK=32 version.
__global__ __launch_bounds__(256) void gemmqkv_kernel(
    const bf16* __restrict__ A, const bf16* __restrict__ Bt,
    const float* __restrict__ bq, const float* __restrict__ bk,
    const float* __restrict__ bv,
    bf16* __restrict__ Qb, bf16* __restrict__ Kb, bf16* __restrict__ Vt) {
  const int K = HIDDEN;
  __shared__ bf16 sA[2][128 * 64];
  __shared__ bf16 sB[2][64 * 64];
  __shared__ bf16 strans[4][16][20];

  int bid = blockIdx.x;
  int bm = bid / 36, bn = bid - bm * 36;
  int tid = threadIdx.x;
  int w = tid >> 6, l = tid & 63;
  int wr = w >> 1, wc = w & 1;
  int l15 = l & 15, g = l >> 4;
  const int sw = l15 & 7;

  const bf16* Ab = A + (size_t)bm * 128 * K;
  const bf16* Bb = Bt + (size_t)bn * 64 * K;

  int sr = tid >> 3;                    // staging row 0..31
  int scs = ((tid & 7) ^ (sr & 7)) << 3; // pre-swizzled source col (elems)

  f32x4 acc[4][2] = {};
  int NT = K >> 6;                       // 12
  int cur = 0;

  auto stage = [&](int buf, int kt) {
    const bf16* ga = Ab + (size_t)sr * K + kt * 64 + scs;
    bf16* la = &sA[buf][w << 9];
    gload_lds16(ga, la);                          // rows 0..31
    gload_lds16(ga + (size_t)32 * K, la + 2048);  // rows 32..63
    gload_lds16(ga + (size_t)64 * K, la + 4096);  // rows 64..95
    gload_lds16(ga + (size_t)96 * K, la + 6144);  // rows 96..127
    const bf16* gb = Bb + (size_t)sr * K + kt * 64 + scs;
    bf16* lb = &sB[buf][w << 9];
    gload_lds16(gb, lb);                          // rows 0..31
    gload_lds16(gb + (size_t)32 * K, lb + 2048);  // rows 32..63
  };

  stage(0, 0);
  for (int kt = 0; kt < NT; ++kt) {
    __syncthreads();
    if (kt + 1 < NT) stage(cur ^ 1, kt + 1);
    const bf16* pa = &sA[cur][0];
    const bf16* pb = &sB[cur][0];
    bf16x8 af[2][4], bfr[2][2];
#pragma unroll
    for (int kh = 0; kh < 2; ++kh) {
#pragma unroll
      for (int m = 0; m < 4; ++m)
        af[kh][m] = *(const bf16x8*)&pa[(wr * 64 + m * 16 + l15) * 64 +
                                        (((kh * 4 + g) ^ sw) << 3)];
#pragma unroll
      for (int n = 0; n < 2; ++n)
        bfr[kh][n] = *(const bf16x8*)&pb[(wc * 32 + n * 16 + l15) * 64 +
                                         (((kh * 4 + g) ^ sw) << 3)];
    }
#pragma unroll
    for (int kh = 0; kh < 2; ++kh)
#pragma unroll
      for (int m = 0; m < 4; ++m)
#pragma unroll
        for (int n = 0; n < 2; ++n)
          acc[m][n] = __builtin_amdgcn_mfma_f32_16x16x32_bf16(af[kh][m], bfr[kh][n],
                                                              acc[m][n], 0, 0, 0);
    cur ^= 1;
  }

  const int mat = bn / 12;           // 0=Q 1=K 2=V (12 head-tiles per matrix)
  const int h = bn - mat * 12;
  const float* bias = (mat == 0) ? bq : (mat == 1) ? bk : bv;
  const float scl = (mat == 0) ? QSCALE : 1.0f;

#pragma unroll
  for (int n = 0; n < 2; ++n) {
    int e = wc * 32 + n * 16 + l15;  // 0..63 within the head
    float bb = bias[h * 64 + e];
#pragma unroll
    for (int m = 0; m < 4; ++m) {
      int s0m = bm * 128 + wr * 64 + m * 16;
      if (mat < 2) {
        bf16* dst = (mat == 0 ? Qb : Kb) + (size_t)h * SEQ * 64;
#pragma unroll
        for (int r = 0; r < 4; ++r)
          dst[(size_t)(s0m + g * 4 + r) * 64 + e] = __float2bfloat16((acc[m][n][r] + bb) * scl);
      } else {
#pragma unroll
        for (int r = 0; r < 4; ++r)
          strans[w][g * 4 + r][l15] = __float2bfloat16(acc[m][n][r] + bb);
        int e0f = e - l15;
        bf16* dst = Vt + (size_t)h * SEQ * 64;
#pragma unroll
        for (int r = 0; r < 4; ++r) {
          bf16 val = strans[w][l15][g * 4 + r];
          dst[(size_t)(e0f + g * 4 + r) * SEQ + s0m + l15] = val;
        }
      }
    }
  }
}

// ---- GEMM64 (64x64 tile, BK=64, XOR-swizzled LDS): out = ctx*Wot^T + bo -----
__global__ __launch_bounds__(256) void gemm64_kernel(
    const bf16* __restrict__ A, const bf16* __restrict__ Bt,
    int K, int ntn, const float* __restrict__ bo, float* __restrict__ outp) {
  __shared__ bf16 sA[2][64 * 64];
  __shared__ bf16 sB[2][64 * 64];

  int bid = blockIdx.x;
  int bm = bid / ntn, bn = bid - bm * ntn;
  int tid = threadIdx.x;
  int w = tid >> 6, l = tid & 63;
  int wr = w >> 1, wc = w & 1;
  int l15 = l & 15, g = l >> 4;
  const int sw = l15 & 7;

  const bf16* Ab = A + (size_t)bm * 64 * K;
  const bf16* Bb = Bt + (size_t)bn * 64 * K;

  int sr = tid >> 3;                    // staging row 0..31
  int scs = ((tid & 7) ^ (sr & 7)) << 3; // pre-swizzled source col (elems)

  f32x4 acc[2][2] = {};
  int NT = K >> 6;                       // 12
  int cur = 0;

  auto stage = [&](int buf, int kt) {
    const bf16* ga = Ab + (size_t)sr * K + kt * 64 + scs;
    bf16* la = &sA[buf][w << 9];
    gload_lds16(ga, la);
    gload_lds16(ga + (size_t)32 * K, la + 2048);
    const bf16* gb = Bb + (size_t)sr * K + kt * 64 + scs;
    bf16* lb = &sB[buf][w << 9];
    gload_lds16(gb, lb);
    gload_lds16(gb + (size_t)32 * K, lb + 2048);
  };

  stage(0, 0);
  for (int kt = 0; kt < NT; ++kt) {
    __syncthreads();
    if (kt + 1 < NT) stage(cur ^ 1, kt + 1);
    const bf16* pa = &sA[cur][0];
    const bf16* pb = &sB[cur][0];
    bf16x8 af[2][2], bfr[2][2];
#pragma unroll
    for (int kh = 0; kh < 2; ++kh) {
#pragma unroll
      for (int m = 0; m < 2; ++m)
        af[kh][m] = *(const bf16x8*)&pa[(wr * 32 + m * 16 + l15) * 64 +
                                        (((kh * 4 + g) ^ sw) << 3)];
#pragma unroll
      for (int n = 0; n < 2; ++n)
        bfr[kh][n] = *(const bf16x8*)&pb[(wc * 32 + n * 16 + l15) * 64 +
                                         (((kh * 4 + g) ^ sw) << 3)];
    }
#pragma unroll
    for (int kh = 0; kh < 2; ++kh)
#pragma unroll
      for (int m = 0; m < 2; ++m)
#pragma unroll
        for (int n = 0; n < 2; ++n)
          acc[m][n] = __builtin_amdgcn_mfma_f32_16x16x32_bf16(af[kh][m], bfr[kh][n],
                                                              acc[m][n], 0, 0, 0);
    cur ^= 1;
  }

#pragma unroll
  for (int n = 0; n < 2; ++n) {
    int j = bn * 64 + wc * 32 + n * 16 + l15;
    float bb = bo[j];
#pragma unroll
    for (int m = 0; m < 2; ++m) {
      int s0m = bm * 64 + wr * 32 + m * 16;
#pragma unroll
      for (int r = 0; r < 4; ++r)
        outp[(size_t)(s0m + g * 4 + r) * HIDDEN + j] = acc[m][n][r] + bb;
    }
  }
}

// ---------------- flash attention v19: split-KV x2 (R23 winner, unchanged) ---
__global__ __launch_bounds__(512, 8) void flash_kernel(
    const bf16* __restrict__ Qb, const bf16* __restrict__ Kb,
    const bf16* __restrict__ Vt, bf16* __restrict__ partC,
    float* __restrict__ partM, float* __restrict__ partL) {
  __shared__ bf16 sK[2][64 * 64];   // [t][e], 128B rows, swizzled
  __shared__ bf16 sV[2][64 * 64];   // [e][t], 128B rows, swizzled

  const int head = blockIdx.y;
  const int split = blockIdx.z;
  const int w = threadIdx.x >> 6, l = threadIdx.x & 63;
  const int l15 = l & 15, g = l >> 4;
  const int sw = l15 & 7;
  const int q0w = blockIdx.x * 128 + w * 16;

  const bf16* Qh = Qb + (size_t)head * SEQ * 64;
  const bf16* Kh = Kb + (size_t)head * SEQ * 64;
  const bf16* Vh = Vt + (size_t)head * SEQ * 64;   // [64][SEQ]

  // Q as B-operand: lane holds Q[col=q0w+l15][k-slice g]
  bf16x8 aq[2];
  aq[0] = *(const bf16x8*)&Qh[(size_t)(q0w + l15) * 64 + g * 8];
  aq[1] = *(const bf16x8*)&Qh[(size_t)(q0w + l15) * 64 + 32 + g * 8];

  float mrun = -1e30f, lsum = 0.f;   // mrun row-uniform (updated only in branch)
  f32x4 cacc[4] = {};

  const int lr8 = l >> 3;            // row-in-call 0..7
  const int csrc = (l & 7) ^ lr8;    // pre-swizzled source chunk

  // wave w stages K rows [w*8, w*8+8) and V rows [w*8, w*8+8)
  auto stage = [&](int buf, int kt) {
    int t0 = kt * 64;
    const bf16* gk = Kh + (size_t)(t0 + w * 8 + lr8) * 64 + csrc * 8;
    gload_lds16(gk, &sK[buf][(w * 8) * 64]);
    const bf16* gv = Vh + (size_t)(w * 8 + lr8) * SEQ + t0 + csrc * 8;
    gload_lds16(gv, &sV[buf][(w * 8) * 64]);
  };

  const int kt0 = split * (SEQ / 64 / NSPLIT);
  stage(0, kt0);

#pragma unroll
  for (int it = 0; it < SEQ / 64 / NSPLIT; ++it) {
    const int kt = kt0 + it;
    __syncthreads();               // drains prev stage (vmcnt) + protects buffers
    if (it + 1 < SEQ / 64 / NSPLIT) stage((it + 1) & 1, kt + 1);
    const bf16* kb = &sK[it & 1][0];   // static LDS base after unroll
    const bf16* vb = &sV[it & 1][0];

    // ---- S^T = K·Q^T: lane holds S[t=n*16+g*4+r][q=l15] ----
    f32x4 sc8[4] = {};
    __builtin_amdgcn_s_setprio(1);
#pragma unroll
    for (int n = 0; n < 4; ++n) {
      bf16x8 b0 = *(const bf16x8*)&kb[(n * 16 + l15) * 64 + (g ^ sw) * 8];
      bf16x8 b1 = *(const bf16x8*)&kb[(n * 16 + l15) * 64 + ((4 + g) ^ sw) * 8];
      sc8[n] = __builtin_amdgcn_mfma_f32_16x16x32_bf16(b0, aq[0], sc8[n], 0, 0, 0);
      sc8[n] = __builtin_amdgcn_mfma_f32_16x16x32_bf16(b1, aq[1], sc8[n], 0, 0, 0);
    }
    __builtin_amdgcn_s_setprio(0);

    // ---- lane-local quarter max (max3 groups, NO shuffles) ----
    float m0 = max3f(sc8[0][0], sc8[0][1], sc8[0][2]);
    float m1 = max3f(sc8[0][3], sc8[1][0], sc8[1][1]);
    float m2 = max3f(sc8[1][2], sc8[1][3], sc8[2][0]);
    float m3 = max3f(sc8[2][1], sc8[2][2], sc8[2][3]);
    float m4 = max3f(sc8[3][0], sc8[3][1], sc8[3][2]);
    float qmax = fmaxf(max3f(m0, m1, m2), max3f(m3, m4, sc8[3][3]));

    // ---- lazy defer-rescale: full row reduce only inside the rare branch ----
    if (__any(qmax > mrun + 8.0f)) {
      float vm = qmax;
      vm = fmaxf(vm, __shfl_xor(vm, 16));
      vm = fmaxf(vm, __shfl_xor(vm, 32));
      float mn = fmaxf(mrun, vm);
      float a = __builtin_amdgcn_exp2f(mrun - mn);
      mrun = mn;
      lsum *= a;
      float aqr[4];
#pragma unroll
      for (int r = 0; r < 4; ++r) aqr[r] = __shfl(a, g * 4 + r);
#pragma unroll
      for (int f = 0; f < 4; ++f)
#pragma unroll
        for (int r = 0; r < 4; ++r) cacc[f][r] *= aqr[r];
    }

    // ---- P = exp2(S - m), packed in-register ----
    unsigned X[4][2];
    float ls0 = 0.f, ls1 = 0.f;
#pragma unroll
    for (int n = 0; n < 4; ++n) {
#pragma unroll
      for (int h = 0; h < 2; ++h) {
        float p0 = __builtin_amdgcn_exp2f(sc8[n][2 * h] - mrun);
        float p1 = __builtin_amdgcn_exp2f(sc8[n][2 * h + 1] - mrun);
        ls0 += p0; ls1 += p1;
        X[n][h] = cvt_pk_bf16(p0, p1);
      }
    }
    lsum += ls0 + ls1;

    // ---- route packed P into PV A-frags (permlane-only, R15-validated) ----
#pragma unroll
    for (int kkl = 0; kkl < 2; ++kkl) {
      unsigned P0 = X[2 * kkl][0], Q0 = X[2 * kkl + 1][0];
      unsigned P1 = X[2 * kkl][1], Q1 = X[2 * kkl + 1][1];
      asm("v_permlane32_swap_b32 %0, %1" : "+v"(P0), "+v"(Q0));
      asm("v_permlane32_swap_b32 %0, %1" : "+v"(P1), "+v"(Q1));
      asm("v_permlane16_swap_b32 %0, %1" : "+v"(P0), "+v"(Q0));
      asm("v_permlane16_swap_b32 %0, %1" : "+v"(P1), "+v"(Q1));
      union { unsigned u[4]; bf16x8 v8; } ap;
      ap.u[0] = P0;
      ap.u[1] = P1;
      ap.u[2] = Q0;
      ap.u[3] = Q1;
      __builtin_amdgcn_s_setprio(1);
#pragma unroll
      for (int f = 0; f < 4; ++f) {
        bf16x8 bv8 = *(const bf16x8*)&vb[(f * 16 + l15) * 64 + ((kkl * 4 + g) ^ sw) * 8];
        cacc[f] = __builtin_amdgcn_mfma_f32_16x16x32_bf16(ap.v8, bv8, cacc[f], 0, 0, 0);
      }
      __builtin_amdgcn_s_setprio(0);
    }
  }

  // ---- epilogue: reduce l across g (R15 shfl_xor), store partials ----
  float s = lsum;
  s += __shfl_xor(s, 16);
  s += __shfl_xor(s, 32);

  bf16* pcw = partC + (size_t)split * SEQ * HIDDEN;
#pragma unroll
  for (int f = 0; f < 4; ++f)
#pragma unroll
    for (int r = 0; r < 4; ++r)
      pcw[(size_t)(q0w + g * 4 + r) * HIDDEN + head * 64 + f * 16 + l15] =
          __float2bfloat16(cacc[f][r]);
  if (l < 16) {
    size_t mi = (size_t)split * HEADS * SEQ + (size_t)head * SEQ + q0w + l15;
    partM[mi] = mrun;
    partL[mi] = s;
  }
}

// ---------------- split-KV combine (NSPLIT-way exact merge, bf16 partials) ----
__global__ __launch_bounds__(256) void combine_kernel(
    const bf16* __restrict__ partC, const float* __restrict__ partM,
    const float* __restrict__ partL, bf16* __restrict__ ctx) {
  int i = blockIdx.x * 256 + threadIdx.x;   // 4 elems per thread
  int idx = i * 4;
  int s = idx / HIDDEN, c = idx - s * HIDDEN;
  int h = c >> 6;
  size_t mi = (size_t)h * SEQ + s;
  float m[NSPLIT], lv[NSPLIT];
  float ms = -1e30f;
#pragma unroll
  for (int sp = 0; sp < NSPLIT; ++sp) {
    m[sp] = partM[(size_t)sp * HEADS * SEQ + mi];
    lv[sp] = partL[(size_t)sp * HEADS * SEQ + mi];
    ms = fmaxf(ms, m[sp]);
  }
  float wgt[NSPLIT];
  float denom = 0.f;
#pragma unroll
  for (int sp = 0; sp < NSPLIT; ++sp) {
    wgt[sp] = __builtin_amdgcn_exp2f(m[sp] - ms);
    denom += lv[sp] * wgt[sp];
  }
  float inv = 1.0f / denom;
  float ax = 0.f, ay = 0.f, az = 0.f, aw = 0.f;
#pragma unroll
  for (int sp = 0; sp < NSPLIT; ++sp) {
    short4 c4 = ((const short4*)(partC + (size_t)sp * SEQ * HIDDEN))[i];
    ax += b2f(c4.x) * wgt[sp];
    ay += b2f(c4.y) * wgt[sp];
    az += b2f(c4.z) * wgt[sp];
    aw += b2f(c4.w) * wgt[sp];
  }
  union { bf16 h4[4]; short4 s4; } u;
  u.h4[0] = __float2bfloat16(ax * inv);
  u.h4[1] = __float2bfloat16(ay * inv);
  u.h4[2] = __float2bfloat16(az * inv);
  u.h4[3] = __float2bfloat16(aw * inv);
  ((short4*)ctx)[i] = u.s4;
}

// ---------------- launcher ----------------
extern "C" void kernel_launch(void* const* d_in, const int* in_sizes, int n_in,
                              void* d_out, int out_size, void* d_ws, size_t ws_size,
                              hipStream_t stream) {
  const float* x = (const float*)d_in[0];
  const float* Wq = (const float*)d_in[1];
  const float* Wk = (const float*)d_in[2];
  const float* Wv = (const float*)d_in[3];
  const float* bq = (const float*)d_in[4];
  const float* bk = (const float*)d_in[5];
  const float* bv = (const float*)d_in[6];
  const float* Wo = (const float*)d_in[7];
  const float* bo = (const float*)d_in[8];
  float* outp = (float*)d_out;

  char* ws = (char*)d_ws;
  bf16* xb = (bf16*)ws;   ws += (size_t)SEQ * HIDDEN * 2;
  bf16* Wt = (bf16*)ws;   ws += (size_t)3 * HIDDEN * HIDDEN * 2;
  bf16* Wot = (bf16*)ws;  ws += (size_t)HIDDEN * HIDDEN * 2;
  bf16* Qb = (bf16*)ws;   ws += (size_t)SEQ * HIDDEN * 2;
  bf16* Kb = (bf16*)ws;   ws += (size_t)SEQ * HIDDEN * 2;
  bf16* Vt = (bf16*)ws;   ws += (size_t)SEQ * HIDDEN * 2;
  bf16* ctx = (bf16*)ws;  ws += (size_t)SEQ * HIDDEN * 2;
  bf16* partC = (bf16*)ws;  ws += (size_t)NSPLIT * SEQ * HIDDEN * 2;
  float* partM = (float*)ws; ws += (size_t)NSPLIT * HEADS * SEQ * 4;
  float* partL = (float*)ws; ws += (size_t)NSPLIT * HEADS * SEQ * 4;

  prep_kernel<<<3648, 256, 0, stream>>>(x, Wq, Wk, Wv, Wo, xb, Wt, Wot);

  gemmqkv_kernel<<<32 * 36, 256, 0, stream>>>(xb, Wt, bq, bk, bv, Qb, Kb, Vt);

  flash_kernel<<<dim3(SEQ / 128, HEADS, NSPLIT), 512, 0, stream>>>(Qb, Kb, Vt,
                                                                   partC, partM, partL);
  combine_kernel<<<SEQ * HIDDEN / 4 / 256, 256, 0, stream>>>(partC, partM, partL, ctx);

  gemm64_kernel<<<64 * 12, 256, 0, stream>>>(ctx, Wot, 768, 12, bo, outp);
}